// Round 1
// baseline (105.506 us; speedup 1.0000x reference)
//
#include <hip/hip_runtime.h>

// MetaLSTM: T=32 timesteps, B=262144 independent batch elements, H=16.
// Per-element recurrence:
//   f = dot(x_t, WF[0:16]) + cS*WF[16] + fS*WF[17] + bF
//   i = dot(x_t, WI[0:16]) + cS*WI[16] + iS*WI[17] + bI
//   d = m*dS - sigmoid(i)*g_t
//   c = sigmoid(f)*cS + d
// Outputs (flattened concat): fS[B], iS[B], cS[B], dS[B]

__device__ __forceinline__ float sigmoidf_(float v) {
    return 1.0f / (1.0f + __expf(-v));
}

__global__ __launch_bounds__(256) void metalstm_kernel(
    const float* __restrict__ x,      // [T, B, 16]
    const float* __restrict__ grads,  // [T, B, 1]
    const float* __restrict__ WF,     // [18, 1]
    const float* __restrict__ WI,     // [18, 1]
    const float* __restrict__ cI,     // [B, 1]
    const float* __restrict__ bI,     // [1, 1]
    const float* __restrict__ bF,     // [1, 1]
    const float* __restrict__ mp,     // [1]
    float* __restrict__ out,          // [4*B]
    int B, int T)
{
    int b = blockIdx.x * blockDim.x + threadIdx.x;
    if (b >= B) return;

    // Wave-uniform weight loads (broadcast; cached after first wave).
    float wf[18], wi[18];
#pragma unroll
    for (int k = 0; k < 18; ++k) { wf[k] = WF[k]; wi[k] = WI[k]; }
    const float bf = bF[0];
    const float bi = bI[0];
    const float m  = mp[0];

    float fS = 0.0f, iS = 0.0f, cS = cI[b], dS = 0.0f;

    // x viewed as float4: row (t,b) starts at float4 index (t*B + b)*4
    const float4* __restrict__ xv = reinterpret_cast<const float4*>(x);
    const size_t xbase   = (size_t)b * 4;
    const size_t xstride = (size_t)B * 4;

#pragma unroll 4
    for (int t = 0; t < T; ++t) {
        const float4* xp = xv + xbase + (size_t)t * xstride;
        float4 a0 = xp[0];
        float4 a1 = xp[1];
        float4 a2 = xp[2];
        float4 a3 = xp[3];
        float gt = grads[(size_t)t * B + b];

        float df = a0.x * wf[0];
        df = fmaf(a0.y, wf[1],  df);
        df = fmaf(a0.z, wf[2],  df);
        df = fmaf(a0.w, wf[3],  df);
        df = fmaf(a1.x, wf[4],  df);
        df = fmaf(a1.y, wf[5],  df);
        df = fmaf(a1.z, wf[6],  df);
        df = fmaf(a1.w, wf[7],  df);
        df = fmaf(a2.x, wf[8],  df);
        df = fmaf(a2.y, wf[9],  df);
        df = fmaf(a2.z, wf[10], df);
        df = fmaf(a2.w, wf[11], df);
        df = fmaf(a3.x, wf[12], df);
        df = fmaf(a3.y, wf[13], df);
        df = fmaf(a3.z, wf[14], df);
        df = fmaf(a3.w, wf[15], df);

        float di = a0.x * wi[0];
        di = fmaf(a0.y, wi[1],  di);
        di = fmaf(a0.z, wi[2],  di);
        di = fmaf(a0.w, wi[3],  di);
        di = fmaf(a1.x, wi[4],  di);
        di = fmaf(a1.y, wi[5],  di);
        di = fmaf(a1.z, wi[6],  di);
        di = fmaf(a1.w, wi[7],  di);
        di = fmaf(a2.x, wi[8],  di);
        di = fmaf(a2.y, wi[9],  di);
        di = fmaf(a2.z, wi[10], di);
        di = fmaf(a2.w, wi[11], di);
        di = fmaf(a3.x, wi[12], di);
        di = fmaf(a3.y, wi[13], di);
        di = fmaf(a3.z, wi[14], di);
        di = fmaf(a3.w, wi[15], di);

        float f_new = fmaf(cS, wf[16], fmaf(fS, wf[17], df + bf));
        float i_new = fmaf(cS, wi[16], fmaf(iS, wi[17], di + bi));
        float d_new = fmaf(m, dS, -sigmoidf_(i_new) * gt);
        float c_new = fmaf(sigmoidf_(f_new), cS, d_new);

        fS = f_new; iS = i_new; cS = c_new; dS = d_new;
    }

    out[b]             = fS;
    out[(size_t)B + b] = iS;
    out[2*(size_t)B + b] = cS;
    out[3*(size_t)B + b] = dS;
}

extern "C" void kernel_launch(void* const* d_in, const int* in_sizes, int n_in,
                              void* d_out, int out_size, void* d_ws, size_t ws_size,
                              hipStream_t stream) {
    const float* x     = (const float*)d_in[0];
    const float* grads = (const float*)d_in[1];
    const float* WF    = (const float*)d_in[2];
    const float* WI    = (const float*)d_in[3];
    const float* cI    = (const float*)d_in[4];
    const float* bI    = (const float*)d_in[5];
    const float* bF    = (const float*)d_in[6];
    const float* m     = (const float*)d_in[7];
    float* out = (float*)d_out;

    const int T = 32;
    const int B = in_sizes[4];  // cI has B elements

    dim3 block(256);
    dim3 grid((B + 255) / 256);
    metalstm_kernel<<<grid, block, 0, stream>>>(x, grads, WF, WI, cI, bI, bF, m,
                                                out, B, T);
}

// Round 3
// 94.986 us; speedup vs baseline: 1.1108x; 1.1108x over previous
//
#include <hip/hip_runtime.h>

// MetaLSTM: T=32, B=262144, H=16. 4 lanes cooperate per batch element:
// lane l -> b = global_tid>>2, quarter q = l&3 (4 floats of the H=16 dot).
// Per-instruction x loads are perfectly coalesced (contiguous float4/lane).
// Quad-reduce via __shfl_xor(.,1/2,4); recurrence redundant in all 4 lanes.
// Outputs (flattened concat): fS[B], iS[B], cS[B], dS[B]

typedef float f32x4 __attribute__((ext_vector_type(4)));

__device__ __forceinline__ float sigmoidf_(float v) {
    return 1.0f / (1.0f + __expf(-v));
}

__global__ __launch_bounds__(256) void metalstm_kernel(
    const float* __restrict__ x,      // [T, B, 16]
    const float* __restrict__ grads,  // [T, B, 1]
    const float* __restrict__ WF,     // [18, 1]
    const float* __restrict__ WI,     // [18, 1]
    const float* __restrict__ cI,     // [B, 1]
    const float* __restrict__ bI,     // [1, 1]
    const float* __restrict__ bF,     // [1, 1]
    const float* __restrict__ mp,     // [1]
    float* __restrict__ out,          // [4*B]
    int B, int T)
{
    const int tid = blockIdx.x * blockDim.x + threadIdx.x; // 0 .. 4B-1
    const int b   = tid >> 2;
    const int q   = tid & 3;
    if (b >= B) return;

    // Per-lane weight quarter: WF[q*4 .. q*4+3] as one float4 (16B aligned).
    const f32x4 wfv = reinterpret_cast<const f32x4*>(WF)[q];
    const f32x4 wiv = reinterpret_cast<const f32x4*>(WI)[q];
    const float wf16 = WF[16], wf17 = WF[17];
    const float wi16 = WI[16], wi17 = WI[17];
    const float bf = bF[0];
    const float bi = bI[0];
    const float m  = mp[0];

    float fS = 0.0f, iS = 0.0f, cS = cI[b], dS = 0.0f;

    // x as f32x4: element (t, b, q) is vector index (t*B + b)*4 + q.
    const f32x4* __restrict__ xv = reinterpret_cast<const f32x4*>(x);
    const size_t xoff    = (size_t)b * 4 + q;
    const size_t xstride = (size_t)B * 4;

#pragma unroll 8
    for (int t = 0; t < T; ++t) {
        f32x4 a = __builtin_nontemporal_load(xv + xoff + (size_t)t * xstride);
        float gt = __builtin_nontemporal_load(grads + (size_t)t * B + b);

        float df = a.x * wfv.x;
        df = fmaf(a.y, wfv.y, df);
        df = fmaf(a.z, wfv.z, df);
        df = fmaf(a.w, wfv.w, df);

        float di = a.x * wiv.x;
        di = fmaf(a.y, wiv.y, di);
        di = fmaf(a.z, wiv.z, di);
        di = fmaf(a.w, wiv.w, di);

        // Quad reduction (lanes q=0..3 of the same b). Not in the serial
        // recurrence chain -> pipelines across the unroll.
        df += __shfl_xor(df, 1, 4);
        df += __shfl_xor(df, 2, 4);
        di += __shfl_xor(di, 1, 4);
        di += __shfl_xor(di, 2, 4);

        float f_new = fmaf(cS, wf16, fmaf(fS, wf17, df + bf));
        float i_new = fmaf(cS, wi16, fmaf(iS, wi17, di + bi));
        float d_new = fmaf(m, dS, -sigmoidf_(i_new) * gt);
        float c_new = fmaf(sigmoidf_(f_new), cS, d_new);

        fS = f_new; iS = i_new; cS = c_new; dS = d_new;
    }

    if (q == 0) {
        out[b]               = fS;
        out[(size_t)B + b]   = iS;
        out[2*(size_t)B + b] = cS;
        out[3*(size_t)B + b] = dS;
    }
}

extern "C" void kernel_launch(void* const* d_in, const int* in_sizes, int n_in,
                              void* d_out, int out_size, void* d_ws, size_t ws_size,
                              hipStream_t stream) {
    const float* x     = (const float*)d_in[0];
    const float* grads = (const float*)d_in[1];
    const float* WF    = (const float*)d_in[2];
    const float* WI    = (const float*)d_in[3];
    const float* cI    = (const float*)d_in[4];
    const float* bI    = (const float*)d_in[5];
    const float* bF    = (const float*)d_in[6];
    const float* m     = (const float*)d_in[7];
    float* out = (float*)d_out;

    const int T = 32;
    const int B = in_sizes[4];  // cI has B elements

    const int nthreads = B * 4;
    dim3 block(256);
    dim3 grid((nthreads + 255) / 256);
    metalstm_kernel<<<grid, block, 0, stream>>>(x, grads, WF, WI, cI, bI, bF, m,
                                                out, B, T);
}